// Round 6
// baseline (158.499 us; speedup 1.0000x reference)
//
#include <hip/hip_runtime.h>

// Problem constants
#define B_   4
#define L_   2048
#define C_   512
#define NH_  8
#define HD_  64
#define M_   (B_ * L_)      // 8192 rows
#define N_QKV 1536

typedef __bf16 bf16x8 __attribute__((ext_vector_type(8)));
typedef float floatx4 __attribute__((ext_vector_type(4)));
typedef unsigned short ushort_t;

// pack two fp32 -> bf16 pair (round-half-up; 3 VALU: 2 add + v_perm)
__device__ __forceinline__ unsigned pk2(float a, float b) {
  union { float f; unsigned u; } x, y;
  x.f = a; y.f = b;
  return __builtin_amdgcn_perm(y.u + 0x8000u, x.u + 0x8000u, 0x07060302u);
}

__device__ __forceinline__ ushort_t bf16h(float a) {
  union { float f; unsigned u; } x;
  x.f = a;
  return (ushort_t)((x.u + 0x8000u) >> 16);
}

__device__ __forceinline__ floatx4 mfma16(bf16x8 a, bf16x8 b, floatx4 c) {
  return __builtin_amdgcn_mfma_f32_16x16x32_bf16(a, b, c, 0, 0, 0);
}

__device__ __forceinline__ void gld_lds16(const void* g, void* s) {
  __builtin_amdgcn_global_load_lds(
      (const __attribute__((address_space(1))) unsigned int*)(g),
      (__attribute__((address_space(3))) unsigned int*)(s), 16, 0, 0);
}

// ---------------------------------------------------------------------------
// Fused converts: x -> bf16 [M,512]; w_qkv -> bf16 [1536,512] (T);
// w_proj -> bf16 [512,512] (T).  Blocks: [0,2048) x, [2048,2240) wq, rest wp.
// ---------------------------------------------------------------------------
__global__ __launch_bounds__(256) void convert_all_kernel(
    const float* __restrict__ x, const float* __restrict__ wq,
    const float* __restrict__ wp, ushort_t* __restrict__ xb,
    ushort_t* __restrict__ wqT, ushort_t* __restrict__ wpT) {
  __shared__ ushort_t tile[64][68];
  const int t = threadIdx.x;
  const int bid = blockIdx.x;
  if (bid < 2048) {
    size_t i = ((size_t)bid * 256 + t) * 8;
    float4 a = *(const float4*)(x + i);
    float4 b = *(const float4*)(x + i + 4);
    uint4 o;
    o.x = pk2(a.x, a.y);
    o.y = pk2(a.z, a.w);
    o.z = pk2(b.x, b.y);
    o.w = pk2(b.z, b.w);
    *(uint4*)(xb + i) = o;
    return;
  }
  const float* w;
  ushort_t* wt;
  int N, n0, k0;
  if (bid < 2240) {
    int b2 = bid - 2048;
    w = wq; wt = wqT; N = N_QKV;
    n0 = (b2 % 24) * 64; k0 = (b2 / 24) * 64;
  } else {
    int b2 = bid - 2240;
    w = wp; wt = wpT; N = C_;
    n0 = (b2 & 7) * 64; k0 = (b2 >> 3) * 64;
  }
  const int r = t >> 4, c4 = (t & 15) * 4;
#pragma unroll
  for (int i = 0; i < 4; ++i) {
    int k = r + i * 16;
    float4 v = *(const float4*)(w + (size_t)(k0 + k) * N + n0 + c4);
    uint2 p;
    p.x = pk2(v.x, v.y);
    p.y = pk2(v.z, v.w);
    *(uint2*)&tile[k][c4] = p;
  }
  __syncthreads();
#pragma unroll
  for (int i = 0; i < 4; ++i) {
    int n = r + i * 16;
    uint2 o;
    o.x = (unsigned)tile[c4 + 0][n] | ((unsigned)tile[c4 + 1][n] << 16);
    o.y = (unsigned)tile[c4 + 2][n] | ((unsigned)tile[c4 + 3][n] << 16);
    *(uint2*)(wt + (size_t)(n0 + n) * 512 + k0 + c4) = o;
  }
}

// ---------------------------------------------------------------------------
// qkv = x @ w_qkv + b_qkv, bf16 MFMA, tile 128x128, BK=64.
// Epilogue: Q bf16 [B,NH,L,HD] pre-scaled by log2(e)/8; K bf16 [B,NH,L,HD];
// V in PV-A-fragment blocked layout (see attn).
// ---------------------------------------------------------------------------
__global__ __launch_bounds__(256) void qkv_mfma_kernel(
    const ushort_t* __restrict__ A,   // xb [8192,512]
    const ushort_t* __restrict__ Bt,  // wqkvT [1536,512]
    const float* __restrict__ bias,
    ushort_t* __restrict__ Qd, ushort_t* __restrict__ Kd,
    ushort_t* __restrict__ Vd) {
  __shared__ ushort_t As[2][4096];  // [k-half][128 rows x 32 k]
  __shared__ ushort_t Bs[2][4096];

  const int t = threadIdx.x;
  const int w = t >> 6, l = t & 63;
  const int li = l & 15, lq = l >> 4;
  const int wm = w & 1, wn = w >> 1;
  const int m0 = blockIdx.x * 128;
  const int n0 = blockIdx.y * 128;

  // Staging source permutation for XOR-swizzled LDS (dest stays lane*16)
  const int inner = (l & 7) ^ (l >> 3);
  const int srow = (l >> 3) * 2 + (inner >> 2);
  const int skb = inner & 3;

  const ushort_t* asrc0 = A + (size_t)(m0 + (2 * w) * 16 + srow) * 512 + skb * 8;
  const ushort_t* asrc1 = A + (size_t)(m0 + (2 * w + 1) * 16 + srow) * 512 + skb * 8;
  const ushort_t* bsrc0 = Bt + (size_t)(n0 + (2 * w) * 16 + srow) * 512 + skb * 8;
  const ushort_t* bsrc1 = Bt + (size_t)(n0 + (2 * w + 1) * 16 + srow) * 512 + skb * 8;
  const int qo0 = (2 * w) * 512, qo1 = (2 * w + 1) * 512;

  const int foff = (li >> 1) * 128 + ((((li & 1) * 4 + lq)) ^ (li >> 1)) * 16;

  const floatx4 fz = {0.f, 0.f, 0.f, 0.f};
  floatx4 acc[4][4];
#pragma unroll
  for (int i = 0; i < 4; ++i)
#pragma unroll
    for (int j = 0; j < 4; ++j) acc[i][j] = fz;

  for (int kk = 0; kk < 8; ++kk) {
    __syncthreads();
#pragma unroll
    for (int kh = 0; kh < 2; ++kh) {
      gld_lds16(asrc0 + kh * 32, &As[kh][qo0]);
      gld_lds16(asrc1 + kh * 32, &As[kh][qo1]);
      gld_lds16(bsrc0 + kh * 32, &Bs[kh][qo0]);
      gld_lds16(bsrc1 + kh * 32, &Bs[kh][qo1]);
    }
    asrc0 += 64; asrc1 += 64; bsrc0 += 64; bsrc1 += 64;
    __syncthreads();

#pragma unroll
    for (int kh = 0; kh < 2; ++kh) {
      bf16x8 af[4], bfr[4];
#pragma unroll
      for (int mt = 0; mt < 4; ++mt)
        af[mt] = *(const bf16x8*)((const char*)&As[kh][0] +
                                  (wm * 64 + mt * 16) * 64 + foff);
#pragma unroll
      for (int nt = 0; nt < 4; ++nt)
        bfr[nt] = *(const bf16x8*)((const char*)&Bs[kh][0] +
                                   (wn * 64 + nt * 16) * 64 + foff);
#pragma unroll
      for (int mt = 0; mt < 4; ++mt)
#pragma unroll
        for (int nt = 0; nt < 4; ++nt)
          acc[mt][nt] = mfma16(af[mt], bfr[nt], acc[mt][nt]);
    }
  }

  // Epilogue. C mapping per 16x16 tile: row = lq*4 + r, col = li.
  const int n0g = n0 + wn * 64;
  const int kk2 = n0g >> 9, h = (n0g >> 6) & 7;
  const int mb = m0 + wm * 64;
  const int b = mb >> 11;
  const int bh = b * NH_ + h;
  const float SCQ = 0.18033688011f;  // log2(e)/sqrt(HD)
  float bb[4];
#pragma unroll
  for (int nt = 0; nt < 4; ++nt) bb[nt] = bias[n0g + nt * 16 + li];

  if (kk2 == 0) {  // Q (pre-scaled)
#pragma unroll
    for (int mt = 0; mt < 4; ++mt) {
      int lrow = (mb + mt * 16 + lq * 4) & (L_ - 1);
#pragma unroll
      for (int nt = 0; nt < 4; ++nt) {
        int d = nt * 16 + li;
        ushort_t* p = Qd + ((size_t)bh * L_ + lrow) * HD_ + d;
#pragma unroll
        for (int r = 0; r < 4; ++r)
          p[(size_t)r * HD_] = bf16h((acc[mt][nt][r] + bb[nt]) * SCQ);
      }
    }
  } else if (kk2 == 1) {  // K
#pragma unroll
    for (int mt = 0; mt < 4; ++mt) {
      int lrow = (mb + mt * 16 + lq * 4) & (L_ - 1);
#pragma unroll
      for (int nt = 0; nt < 4; ++nt) {
        int d = nt * 16 + li;
        ushort_t* p = Kd + ((size_t)bh * L_ + lrow) * HD_ + d;
#pragma unroll
        for (int r = 0; r < 4; ++r)
          p[(size_t)r * HD_] = bf16h(acc[mt][nt][r] + bb[nt]);
      }
    }
  } else {  // V: blocked PV-A-fragment layout
#pragma unroll
    for (int mt = 0; mt < 4; ++mt) {
      int tb = mb + mt * 16 + lq * 4;  // token of r=0
      int c = (tb >> 6) & 31;
      int sp = (mt >> 1) & 1;
      int rem = tb & 31;               // = 16*(mt&1) + 4*lq
      int lq2 = rem >> 3;
      int h8 = (rem >> 2) & 1;
#pragma unroll
      for (int nt = 0; nt < 4; ++nt) {
        size_t off = ((size_t)(bh * 32 + c) * 512 +
                      ((sp * 4 + nt) * 4 + lq2) * 16 + li) * 8 + h8 * 4;
        uint2 v;
        v.x = pk2(acc[mt][nt][0] + bb[nt], acc[mt][nt][1] + bb[nt]);
        v.y = pk2(acc[mt][nt][2] + bb[nt], acc[mt][nt][3] + bb[nt]);
        *(uint2*)(Vd + off) = v;
      }
    }
  }
}

// ---------------------------------------------------------------------------
// Flash attention: S^T = K·Q^T formulation, zero LDS for P.
// Occupancy-oriented: 64 q-rows/block (wave owns 16), grid 1024 blocks
// -> 4 blocks/CU resident (LDS 32 KB), 16 waves/CU.
// XCD locality: bh = blockIdx.x & 31 so all 32 q-tile blocks of one (b,h)
// share blockIdx%8 -> same XCD -> K/V stay in that XCD's L2 (2 MB/XCD set).
// 128-key mega-steps: 2 sub-chunks of 64 staged per barrier-pair (8 gld in
// flight per wave).
// Key tiling: key(kt, m=lq*4+r) = 32*(kt>>1) + 8*lq + 4*(kt&1) + r, so the
// S^T accumulators ARE the x32 PV B-fragment (k = 8*lq + 4*kt0 + r).
// Ks: [key][d] with swz(key)=(key&3)|(((key>>3)&1)<<2) on 16B d-blocks.
// Vs: pre-blocked (pure contiguous copy from Vd).
// ---------------------------------------------------------------------------
__global__ __launch_bounds__(256) void attn_kernel(
    const ushort_t* __restrict__ Qg, const ushort_t* __restrict__ Kg,
    const ushort_t* __restrict__ Vb, ushort_t* __restrict__ AO) {
  __shared__ ushort_t Ks[2][4096];
  __shared__ ushort_t Vs[2][4096];

  const int t = threadIdx.x;
  const int w = t >> 6, l = t & 63;
  const int li = l & 15, lq = l >> 4;
  const int bh = blockIdx.x & 31;
  const int m0 = (blockIdx.x >> 5) * 64;

  const ushort_t* ksrc[2];
  const ushort_t* vsrc[2];
  int qoff[2];
#pragma unroll
  for (int u = 0; u < 2; ++u) {
    int q = 2 * w + u;
    int p = q * 64 + l;              // 16B slot within a 64-key sub-chunk
    int key = p >> 3, pb = p & 7;
    int swz = (key & 3) | (((key >> 3) & 1) << 2);
    ksrc[u] = Kg + ((size_t)bh * L_ + key) * HD_ + (pb ^ swz) * 8;
    vsrc[u] = Vb + ((size_t)bh * 32 * 512 + p) * 8;
    qoff[u] = p * 8;                 // ushort offset within sub-buffer
  }

  bf16x8 qf[2];
#pragma unroll
  for (int s = 0; s < 2; ++s)
    qf[s] = *(const bf16x8*)(Qg +
        ((size_t)bh * L_ + m0 + w * 16 + li) * HD_ + 32 * s + lq * 8);

  const floatx4 fz = {0.f, 0.f, 0.f, 0.f};
  floatx4 O[4];
  float lsum = 0.f;
#pragma unroll
  for (int dt = 0; dt < 4; ++dt) O[dt] = fz;

  const int keybase = 8 * (li >> 2) + (li & 3);  // key(kt0=0, sp=0) for lane
  const int xsw = li & 7;                        // = swz(key(kt, li))

  for (int c = 0; c < L_ / 128; ++c) {
    __syncthreads();
#pragma unroll
    for (int j = 0; j < 2; ++j) {
      gld_lds16(ksrc[0] + j * 4096, &Ks[j][qoff[0]]);
      gld_lds16(ksrc[1] + j * 4096, &Ks[j][qoff[1]]);
      gld_lds16(vsrc[0] + j * 4096, &Vs[j][qoff[0]]);
      gld_lds16(vsrc[1] + j * 4096, &Vs[j][qoff[1]]);
    }
    ksrc[0] += 8192; ksrc[1] += 8192;
    vsrc[0] += 8192; vsrc[1] += 8192;
    __syncthreads();

#pragma unroll
    for (int j = 0; j < 2; ++j) {
#pragma unroll
      for (int sp = 0; sp < 2; ++sp) {
        floatx4 sa[2];
#pragma unroll
        for (int k2 = 0; k2 < 2; ++k2) sa[k2] = fz;

#pragma unroll
        for (int k2 = 0; k2 < 2; ++k2) {
          const char* rowb =
              (const char*)&Ks[j][0] + (32 * sp + 4 * k2 + keybase) * 128;
#pragma unroll
          for (int s = 0; s < 2; ++s) {
            bf16x8 kf = *(const bf16x8*)(rowb + ((4 * s + lq) ^ xsw) * 16);
            sa[k2] = mfma16(kf, qf[s], sa[k2]);
          }
        }

        float pv[2][4];
#pragma unroll
        for (int k2 = 0; k2 < 2; ++k2)
#pragma unroll
          for (int r = 0; r < 4; ++r) {
            float e = __builtin_amdgcn_exp2f(sa[k2][r]);
            pv[k2][r] = e;
            lsum += e;
          }
        uint4 pk;
        pk.x = pk2(pv[0][0], pv[0][1]);
        pk.y = pk2(pv[0][2], pv[0][3]);
        pk.z = pk2(pv[1][0], pv[1][1]);
        pk.w = pk2(pv[1][2], pv[1][3]);
        bf16x8 pf = __builtin_bit_cast(bf16x8, pk);

#pragma unroll
        for (int dt = 0; dt < 4; ++dt) {
          bf16x8 vf = *(const bf16x8*)((const char*)&Vs[j][0] +
              sp * 4096 + dt * 1024 + lq * 256 + li * 16);
          O[dt] = mfma16(vf, pf, O[dt]);
        }
      }
    }
  }

  // Epilogue: lane holds O^T: q = m0 + w*16 + li, d = 16dt + 4lq + r.
  const int b = bh >> 3, h = bh & 7;
  float s = lsum;
  s += __shfl_xor(s, 16, 64);
  s += __shfl_xor(s, 32, 64);
  float inv = 1.0f / s;
  int qrow = m0 + w * 16 + li;
  ushort_t* base = AO + ((size_t)(b * L_ + qrow)) * C_ + h * HD_ + 4 * lq;
#pragma unroll
  for (int dt = 0; dt < 4; ++dt) {
    uint2 v;
    v.x = pk2(O[dt][0] * inv, O[dt][1] * inv);
    v.y = pk2(O[dt][2] * inv, O[dt][3] * inv);
    *(uint2*)(base + 16 * dt) = v;
  }
}

// ---------------------------------------------------------------------------
// out = AO @ w_proj + b_proj, bf16 MFMA, fp32 out. Tile 64x128, BK=64.
// ---------------------------------------------------------------------------
__global__ __launch_bounds__(256) void proj_mfma_kernel(
    const ushort_t* __restrict__ A,   // AO bf16 [8192,512]
    const ushort_t* __restrict__ Bt,  // wprojT [512,512]
    const float* __restrict__ bias, float* __restrict__ out) {
  __shared__ ushort_t As[2][2048];
  __shared__ ushort_t Bs[2][4096];

  const int t = threadIdx.x;
  const int w = t >> 6, l = t & 63;
  const int li = l & 15, lq = l >> 4;
  const int wm = w & 1, wn = w >> 1;
  const int m0 = blockIdx.x * 64;
  const int n0 = blockIdx.y * 128;

  const int inner = (l & 7) ^ (l >> 3);
  const int srow = (l >> 3) * 2 + (inner >> 2);
  const int skb = inner & 3;

  const ushort_t* asrc0 = A + (size_t)(m0 + w * 16 + srow) * 512 + skb * 8;
  const ushort_t* bsrc0 = Bt + (size_t)(n0 + (2 * w) * 16 + srow) * 512 + skb * 8;
  const ushort_t* bsrc1 = Bt + (size_t)(n0 + (2 * w + 1) * 16 + srow) * 512 + skb * 8;
  const int ao = w * 512;
  const int qo0 = (2 * w) * 512, qo1 = (2 * w + 1) * 512;

  const int foff = (li >> 1) * 128 + ((((li & 1) * 4 + lq)) ^ (li >> 1)) * 16;

  const floatx4 fz = {0.f, 0.f, 0.f, 0.f};
  floatx4 acc[2][4];
#pragma unroll
  for (int i = 0; i < 2; ++i)
#pragma unroll
    for (int j = 0; j < 4; ++j) acc[i][j] = fz;

  for (int kk = 0; kk < 8; ++kk) {
    __syncthreads();
#pragma unroll
    for (int kh = 0; kh < 2; ++kh) {
      gld_lds16(asrc0 + kh * 32, &As[kh][ao]);
      gld_lds16(bsrc0 + kh * 32, &Bs[kh][qo0]);
      gld_lds16(bsrc1 + kh * 32, &Bs[kh][qo1]);
    }
    asrc0 += 64; bsrc0 += 64; bsrc1 += 64;
    __syncthreads();

#pragma unroll
    for (int kh = 0; kh < 2; ++kh) {
      bf16x8 af[2], bfr[4];
#pragma unroll
      for (int mt = 0; mt < 2; ++mt)
        af[mt] = *(const bf16x8*)((const char*)&As[kh][0] +
                                  (wm * 32 + mt * 16) * 64 + foff);
#pragma unroll
      for (int nt = 0; nt < 4; ++nt)
        bfr[nt] = *(const bf16x8*)((const char*)&Bs[kh][0] +
                                   (wn * 64 + nt * 16) * 64 + foff);
#pragma unroll
      for (int mt = 0; mt < 2; ++mt)
#pragma unroll
        for (int nt = 0; nt < 4; ++nt)
          acc[mt][nt] = mfma16(af[mt], bfr[nt], acc[mt][nt]);
    }
  }

#pragma unroll
  for (int mt = 0; mt < 2; ++mt) {
    int m = m0 + wm * 32 + mt * 16 + lq * 4;
#pragma unroll
    for (int nt = 0; nt < 4; ++nt) {
      int n = n0 + wn * 64 + nt * 16 + li;
      float bb = bias[n];
#pragma unroll
      for (int r = 0; r < 4; ++r)
        out[(size_t)(m + r) * C_ + n] = acc[mt][nt][r] + bb;
    }
  }
}

// ---------------------------------------------------------------------------
// Workspace (ushort offsets):
//   Qd 0 | Kd 4194304 | Vblk 8388608 | AO 12582912 | xb 16777216
//   wqkvT 20971520 | wprojT 21757952      (total ~44 MB)
// ---------------------------------------------------------------------------
extern "C" void kernel_launch(void* const* d_in, const int* in_sizes, int n_in,
                              void* d_out, int out_size, void* d_ws,
                              size_t ws_size, hipStream_t stream) {
  const float* x      = (const float*)d_in[0];
  const float* w_qkv  = (const float*)d_in[1];
  const float* b_qkv  = (const float*)d_in[2];
  const float* w_proj = (const float*)d_in[3];
  const float* b_proj = (const float*)d_in[4];
  float* out = (float*)d_out;

  ushort_t* ws     = (ushort_t*)d_ws;
  ushort_t* Qd     = ws;
  ushort_t* Kd     = ws + 4194304;
  ushort_t* Vd     = ws + 8388608;
  ushort_t* AO     = ws + 12582912;
  ushort_t* xb     = ws + 16777216;
  ushort_t* wqkvT  = ws + 20971520;
  ushort_t* wprojT = ws + 21757952;

  convert_all_kernel<<<2304, 256, 0, stream>>>(x, w_qkv, w_proj, xb, wqkvT,
                                               wprojT);

  dim3 g1(M_ / 128, N_QKV / 128);  // 64 x 12
  qkv_mfma_kernel<<<g1, 256, 0, stream>>>(xb, wqkvT, b_qkv, Qd, Kd, Vd);

  attn_kernel<<<1024, 256, 0, stream>>>(Qd, Kd, Vd, AO);

  dim3 g3(M_ / 64, C_ / 128);      // 128 x 4
  proj_mfma_kernel<<<g3, 256, 0, stream>>>(AO, wprojT, b_proj, out);
}

// Round 7
// 148.536 us; speedup vs baseline: 1.0671x; 1.0671x over previous
//
#include <hip/hip_runtime.h>

// Problem constants
#define B_   4
#define L_   2048
#define C_   512
#define NH_  8
#define HD_  64
#define M_   (B_ * L_)      // 8192 rows
#define N_QKV 1536

typedef __bf16 bf16x8 __attribute__((ext_vector_type(8)));
typedef float floatx4 __attribute__((ext_vector_type(4)));
typedef unsigned short ushort_t;

// pack two fp32 -> bf16 pair (round-half-up; 3 VALU: 2 add + v_perm)
__device__ __forceinline__ unsigned pk2(float a, float b) {
  union { float f; unsigned u; } x, y;
  x.f = a; y.f = b;
  return __builtin_amdgcn_perm(y.u + 0x8000u, x.u + 0x8000u, 0x07060302u);
}

__device__ __forceinline__ ushort_t bf16h(float a) {
  union { float f; unsigned u; } x;
  x.f = a;
  return (ushort_t)((x.u + 0x8000u) >> 16);
}

__device__ __forceinline__ floatx4 mfma16(bf16x8 a, bf16x8 b, floatx4 c) {
  return __builtin_amdgcn_mfma_f32_16x16x32_bf16(a, b, c, 0, 0, 0);
}

__device__ __forceinline__ void gld_lds16(const void* g, void* s) {
  __builtin_amdgcn_global_load_lds(
      (const __attribute__((address_space(1))) unsigned int*)(g),
      (__attribute__((address_space(3))) unsigned int*)(s), 16, 0, 0);
}

// ---------------------------------------------------------------------------
// Fused converts: x -> bf16 [M,512]; w_qkv -> bf16 [1536,512] (T);
// w_proj -> bf16 [512,512] (T).  Blocks: [0,2048) x, [2048,2240) wq, rest wp.
// ---------------------------------------------------------------------------
__global__ __launch_bounds__(256) void convert_all_kernel(
    const float* __restrict__ x, const float* __restrict__ wq,
    const float* __restrict__ wp, ushort_t* __restrict__ xb,
    ushort_t* __restrict__ wqT, ushort_t* __restrict__ wpT) {
  __shared__ ushort_t tile[64][68];
  const int t = threadIdx.x;
  const int bid = blockIdx.x;
  if (bid < 2048) {
    size_t i = ((size_t)bid * 256 + t) * 8;
    float4 a = *(const float4*)(x + i);
    float4 b = *(const float4*)(x + i + 4);
    uint4 o;
    o.x = pk2(a.x, a.y);
    o.y = pk2(a.z, a.w);
    o.z = pk2(b.x, b.y);
    o.w = pk2(b.z, b.w);
    *(uint4*)(xb + i) = o;
    return;
  }
  const float* w;
  ushort_t* wt;
  int N, n0, k0;
  if (bid < 2240) {
    int b2 = bid - 2048;
    w = wq; wt = wqT; N = N_QKV;
    n0 = (b2 % 24) * 64; k0 = (b2 / 24) * 64;
  } else {
    int b2 = bid - 2240;
    w = wp; wt = wpT; N = C_;
    n0 = (b2 & 7) * 64; k0 = (b2 >> 3) * 64;
  }
  const int r = t >> 4, c4 = (t & 15) * 4;
#pragma unroll
  for (int i = 0; i < 4; ++i) {
    int k = r + i * 16;
    float4 v = *(const float4*)(w + (size_t)(k0 + k) * N + n0 + c4);
    uint2 p;
    p.x = pk2(v.x, v.y);
    p.y = pk2(v.z, v.w);
    *(uint2*)&tile[k][c4] = p;
  }
  __syncthreads();
#pragma unroll
  for (int i = 0; i < 4; ++i) {
    int n = r + i * 16;
    uint2 o;
    o.x = (unsigned)tile[c4 + 0][n] | ((unsigned)tile[c4 + 1][n] << 16);
    o.y = (unsigned)tile[c4 + 2][n] | ((unsigned)tile[c4 + 3][n] << 16);
    *(uint2*)(wt + (size_t)(n0 + n) * 512 + k0 + c4) = o;
  }
}

// ---------------------------------------------------------------------------
// qkv = x @ w_qkv + b_qkv, bf16 MFMA, tile 128x64, BK=64.
// Grid 64x24 = 1536 blocks -> 6 blocks/CU (24 KB LDS) for short-K latency
// hiding. 4 waves, each 32m x 64n (2x4 MFMA tiles per kh).
// Epilogue: Q bf16 [B,NH,L,HD] pre-scaled by log2(e)/8; K bf16 [B,NH,L,HD];
// V in PV-A-fragment blocked layout (see attn). Block-uniform Q/K/V branch.
// ---------------------------------------------------------------------------
__global__ __launch_bounds__(256) void qkv_mfma_kernel(
    const ushort_t* __restrict__ A,   // xb [8192,512]
    const ushort_t* __restrict__ Bt,  // wqkvT [1536,512]
    const float* __restrict__ bias,
    ushort_t* __restrict__ Qd, ushort_t* __restrict__ Kd,
    ushort_t* __restrict__ Vd) {
  __shared__ ushort_t As[2][4096];  // [k-half][128 rows x 32 k]
  __shared__ ushort_t Bs[2][2048];  // [k-half][64 rows x 32 k]

  const int t = threadIdx.x;
  const int w = t >> 6, l = t & 63;
  const int li = l & 15, lq = l >> 4;
  const int m0 = blockIdx.x * 128;
  const int n0 = blockIdx.y * 64;

  // Staging source permutation for XOR-swizzled LDS (dest stays lane*16)
  const int inner = (l & 7) ^ (l >> 3);
  const int srow = (l >> 3) * 2 + (inner >> 2);
  const int skb = inner & 3;

  const ushort_t* asrc0 = A + (size_t)(m0 + (2 * w) * 16 + srow) * 512 + skb * 8;
  const ushort_t* asrc1 = A + (size_t)(m0 + (2 * w + 1) * 16 + srow) * 512 + skb * 8;
  const ushort_t* bsrc0 = Bt + (size_t)(n0 + w * 16 + srow) * 512 + skb * 8;
  const int qo0 = (2 * w) * 512, qo1 = (2 * w + 1) * 512;
  const int bo0 = w * 512;

  const int foff = (li >> 1) * 128 + ((((li & 1) * 4 + lq)) ^ (li >> 1)) * 16;

  const floatx4 fz = {0.f, 0.f, 0.f, 0.f};
  floatx4 acc[2][4];
#pragma unroll
  for (int i = 0; i < 2; ++i)
#pragma unroll
    for (int j = 0; j < 4; ++j) acc[i][j] = fz;

  for (int kk = 0; kk < 8; ++kk) {
    __syncthreads();
#pragma unroll
    for (int kh = 0; kh < 2; ++kh) {
      gld_lds16(asrc0 + kh * 32, &As[kh][qo0]);
      gld_lds16(asrc1 + kh * 32, &As[kh][qo1]);
      gld_lds16(bsrc0 + kh * 32, &Bs[kh][bo0]);
    }
    asrc0 += 64; asrc1 += 64; bsrc0 += 64;
    __syncthreads();

#pragma unroll
    for (int kh = 0; kh < 2; ++kh) {
      bf16x8 af[2], bfr[4];
#pragma unroll
      for (int mt = 0; mt < 2; ++mt)
        af[mt] = *(const bf16x8*)((const char*)&As[kh][0] +
                                  (w * 32 + mt * 16) * 64 + foff);
#pragma unroll
      for (int nt = 0; nt < 4; ++nt)
        bfr[nt] = *(const bf16x8*)((const char*)&Bs[kh][0] +
                                   (nt * 16) * 64 + foff);
#pragma unroll
      for (int mt = 0; mt < 2; ++mt)
#pragma unroll
        for (int nt = 0; nt < 4; ++nt)
          acc[mt][nt] = mfma16(af[mt], bfr[nt], acc[mt][nt]);
    }
  }

  // Epilogue. C mapping per 16x16 tile: row = lq*4 + r, col = li.
  const int kk2 = n0 >> 9, h = (n0 >> 6) & 7;
  const int mb = m0 + w * 32;
  const int b = m0 >> 11;
  const int bh = b * NH_ + h;
  const float SCQ = 0.18033688011f;  // log2(e)/sqrt(HD)
  float bb[4];
#pragma unroll
  for (int nt = 0; nt < 4; ++nt) bb[nt] = bias[n0 + nt * 16 + li];

  if (kk2 == 0) {  // Q (pre-scaled)
#pragma unroll
    for (int mt = 0; mt < 2; ++mt) {
      int lrow = (mb + mt * 16 + lq * 4) & (L_ - 1);
#pragma unroll
      for (int nt = 0; nt < 4; ++nt) {
        int d = nt * 16 + li;
        ushort_t* p = Qd + ((size_t)bh * L_ + lrow) * HD_ + d;
#pragma unroll
        for (int r = 0; r < 4; ++r)
          p[(size_t)r * HD_] = bf16h((acc[mt][nt][r] + bb[nt]) * SCQ);
      }
    }
  } else if (kk2 == 1) {  // K
#pragma unroll
    for (int mt = 0; mt < 2; ++mt) {
      int lrow = (mb + mt * 16 + lq * 4) & (L_ - 1);
#pragma unroll
      for (int nt = 0; nt < 4; ++nt) {
        int d = nt * 16 + li;
        ushort_t* p = Kd + ((size_t)bh * L_ + lrow) * HD_ + d;
#pragma unroll
        for (int r = 0; r < 4; ++r)
          p[(size_t)r * HD_] = bf16h(acc[mt][nt][r] + bb[nt]);
      }
    }
  } else {  // V: blocked PV-A-fragment layout
#pragma unroll
    for (int mt = 0; mt < 2; ++mt) {
      int tb = mb + mt * 16 + lq * 4;  // token of r=0 (within batch b's L)
      int key = tb & 63;
      int c = (tb >> 6) & 31;
      int sp = key >> 5;
      int rem = key & 31;
      int lq2 = rem >> 3;
      int h8 = (rem >> 2) & 1;
#pragma unroll
      for (int nt = 0; nt < 4; ++nt) {
        size_t off = ((size_t)(bh * 32 + c) * 512 +
                      ((sp * 4 + nt) * 4 + lq2) * 16 + li) * 8 + h8 * 4;
        uint2 v;
        v.x = pk2(acc[mt][nt][0] + bb[nt], acc[mt][nt][1] + bb[nt]);
        v.y = pk2(acc[mt][nt][2] + bb[nt], acc[mt][nt][3] + bb[nt]);
        *(uint2*)(Vd + off) = v;
      }
    }
  }
}

// ---------------------------------------------------------------------------
// Flash attention: S^T = K·Q^T, zero LDS for P, split-K within block.
// 512 threads = 8 waves; group g2 = w>>4... g2 = w>>2 handles keys
// [g2*1024, g2*1024+1024). Each wave owns 32 q-rows (2 groups of 16) ->
// halves LDS reads per q-row vs 16-row waves. Grid 512 (16 q-tiles x 32 bh)
// -> 2 blocks/CU, 16 waves/CU. XCD locality: bh = blockIdx.x & 31.
// After the main loop, group 1 writes fp32 O-partials + lsum to LDS (reusing
// the K/V buffers); group 0 adds, normalizes, stores. Partial softmax sums
// are exact (no max subtraction).
// ---------------------------------------------------------------------------
__global__ __launch_bounds__(512) void attn_kernel(
    const ushort_t* __restrict__ Qg, const ushort_t* __restrict__ Kg,
    const ushort_t* __restrict__ Vb, ushort_t* __restrict__ AO) {
  __shared__ __align__(16) char smem[35328];
  ushort_t* KsB = (ushort_t*)smem;            // [2][4096] per-group K
  ushort_t* VsB = (ushort_t*)(smem + 16384);  // [2][4096] per-group V
  float* Oc = (float*)smem;                   // reused: [128][68] fp32
  float* Lc = (float*)(smem + 34816);         // [128] fp32

  const int t = threadIdx.x;
  const int w = t >> 6, l = t & 63;
  const int g2 = w >> 2, wl = w & 3;
  const int li = l & 15, lq = l >> 4;
  const int bh = blockIdx.x & 31;
  const int m0 = (blockIdx.x >> 5) * 128;

  ushort_t* Ks = KsB + g2 * 4096;
  ushort_t* Vs = VsB + g2 * 4096;

  const ushort_t* ksrc[2];
  const ushort_t* vsrc[2];
  int koff[2];
#pragma unroll
  for (int u = 0; u < 2; ++u) {
    int p = (2 * wl + u) * 64 + l;   // 16B slot within the 64-key chunk
    int key = p >> 3, pb = p & 7;
    int swz = (key & 3) | (((key >> 3) & 1) << 2);
    ksrc[u] = Kg + ((size_t)bh * L_ + g2 * 1024 + key) * HD_ + (pb ^ swz) * 8;
    vsrc[u] = Vb + ((size_t)bh * 32 * 512 + (size_t)g2 * 16 * 512 + p) * 8;
    koff[u] = p * 8;                 // ushort offset within group buffer
  }

  // Q fragments: rows m0 + wl*32 + 16g + li (both groups load same Q)
  bf16x8 qf[2][2];
#pragma unroll
  for (int g = 0; g < 2; ++g)
#pragma unroll
    for (int s = 0; s < 2; ++s)
      qf[g][s] = *(const bf16x8*)(Qg +
          ((size_t)bh * L_ + m0 + wl * 32 + 16 * g + li) * HD_ + 32 * s + lq * 8);

  const floatx4 fz = {0.f, 0.f, 0.f, 0.f};
  floatx4 O[2][4];
  float lsum[2] = {0.f, 0.f};
#pragma unroll
  for (int g = 0; g < 2; ++g)
#pragma unroll
    for (int dt = 0; dt < 4; ++dt) O[g][dt] = fz;

  const int keybase = 8 * (li >> 2) + (li & 3);
  const int xsw = li & 7;

  for (int c = 0; c < 16; ++c) {
    __syncthreads();
#pragma unroll
    for (int u = 0; u < 2; ++u) {
      gld_lds16(ksrc[u], Ks + koff[u]);
      gld_lds16(vsrc[u], Vs + koff[u]);
      ksrc[u] += 64 * HD_;
      vsrc[u] += 4096;
    }
    __syncthreads();

#pragma unroll
    for (int sp = 0; sp < 2; ++sp) {
      floatx4 sa[2][2];
#pragma unroll
      for (int g = 0; g < 2; ++g)
#pragma unroll
        for (int k2 = 0; k2 < 2; ++k2) sa[g][k2] = fz;

#pragma unroll
      for (int k2 = 0; k2 < 2; ++k2) {
        const char* rowb =
            (const char*)Ks + (32 * sp + 4 * k2 + keybase) * 128;
#pragma unroll
        for (int s = 0; s < 2; ++s) {
          bf16x8 kf = *(const bf16x8*)(rowb + ((4 * s + lq) ^ xsw) * 16);
          sa[0][k2] = mfma16(kf, qf[0][s], sa[0][k2]);
          sa[1][k2] = mfma16(kf, qf[1][s], sa[1][k2]);
        }
      }

      bf16x8 pf[2];
#pragma unroll
      for (int g = 0; g < 2; ++g) {
        float pv[2][4];
#pragma unroll
        for (int k2 = 0; k2 < 2; ++k2)
#pragma unroll
          for (int r = 0; r < 4; ++r) {
            float e = __builtin_amdgcn_exp2f(sa[g][k2][r]);
            pv[k2][r] = e;
            lsum[g] += e;
          }
        uint4 pk;
        pk.x = pk2(pv[0][0], pv[0][1]);
        pk.y = pk2(pv[0][2], pv[0][3]);
        pk.z = pk2(pv[1][0], pv[1][1]);
        pk.w = pk2(pv[1][2], pv[1][3]);
        pf[g] = __builtin_bit_cast(bf16x8, pk);
      }

#pragma unroll
      for (int dt = 0; dt < 4; ++dt) {
        bf16x8 vf = *(const bf16x8*)((const char*)Vs +
            sp * 4096 + dt * 1024 + lq * 256 + li * 16);
        O[0][dt] = mfma16(vf, pf[0], O[0][dt]);
        O[1][dt] = mfma16(vf, pf[1], O[1][dt]);
      }
    }
  }

  // ---- combine the two key-groups through LDS ----
  float srow[2];
#pragma unroll
  for (int g = 0; g < 2; ++g) {
    float s = lsum[g];
    s += __shfl_xor(s, 16, 64);
    s += __shfl_xor(s, 32, 64);
    srow[g] = s;   // total over this group's keys, for row 16g+li
  }

  __syncthreads();   // all K/V reads done; safe to reuse smem as Oc
  if (g2 == 1) {
#pragma unroll
    for (int g = 0; g < 2; ++g) {
      int row = wl * 32 + 16 * g + li;
#pragma unroll
      for (int dt = 0; dt < 4; ++dt)
        *(floatx4*)&Oc[row * 68 + 16 * dt + 4 * lq] = O[g][dt];
      Lc[row] = srow[g];
    }
  }
  __syncthreads();

  if (g2 == 0) {
    const int b = bh >> 3, h = bh & 7;
#pragma unroll
    for (int g = 0; g < 2; ++g) {
      int row = wl * 32 + 16 * g + li;
      float inv = 1.0f / (srow[g] + Lc[row]);
      int qrow = m0 + row;
      ushort_t* base = AO + ((size_t)(b * L_ + qrow)) * C_ + h * HD_ + 4 * lq;
#pragma unroll
      for (int dt = 0; dt < 4; ++dt) {
        floatx4 oc = *(const floatx4*)&Oc[row * 68 + 16 * dt + 4 * lq];
        floatx4 ot = O[g][dt] + oc;
        uint2 v;
        v.x = pk2(ot[0] * inv, ot[1] * inv);
        v.y = pk2(ot[2] * inv, ot[3] * inv);
        *(uint2*)(base + 16 * dt) = v;
      }
    }
  }
}

// ---------------------------------------------------------------------------
// out = AO @ w_proj + b_proj, bf16 MFMA, fp32 out. Tile 64x64, BK=64.
// Grid 128x8 = 1024 blocks -> 4 blocks/CU. Wave = 16m x 64n.
// ---------------------------------------------------------------------------
__global__ __launch_bounds__(256) void proj_mfma_kernel(
    const ushort_t* __restrict__ A,   // AO bf16 [8192,512]
    const ushort_t* __restrict__ Bt,  // wprojT [512,512]
    const float* __restrict__ bias, float* __restrict__ out) {
  __shared__ ushort_t As[2][2048];  // [k-half][64 rows x 32 k]
  __shared__ ushort_t Bs[2][2048];

  const int t = threadIdx.x;
  const int w = t >> 6, l = t & 63;
  const int li = l & 15, lq = l >> 4;
  const int m0 = blockIdx.x * 64;
  const int n0 = blockIdx.y * 64;

  const int inner = (l & 7) ^ (l >> 3);
  const int srow = (l >> 3) * 2 + (inner >> 2);
  const int skb = inner & 3;

  const ushort_t* asrc0 = A + (size_t)(m0 + w * 16 + srow) * 512 + skb * 8;
  const ushort_t* bsrc0 = Bt + (size_t)(n0 + w * 16 + srow) * 512 + skb * 8;
  const int qo0 = w * 512;

  const int foff = (li >> 1) * 128 + ((((li & 1) * 4 + lq)) ^ (li >> 1)) * 16;

  const floatx4 fz = {0.f, 0.f, 0.f, 0.f};
  floatx4 acc[4];
#pragma unroll
  for (int j = 0; j < 4; ++j) acc[j] = fz;

  for (int kk = 0; kk < 8; ++kk) {
    __syncthreads();
#pragma unroll
    for (int kh = 0; kh < 2; ++kh) {
      gld_lds16(asrc0 + kh * 32, &As[kh][qo0]);
      gld_lds16(bsrc0 + kh * 32, &Bs[kh][qo0]);
    }
    asrc0 += 64; bsrc0 += 64;
    __syncthreads();

#pragma unroll
    for (int kh = 0; kh < 2; ++kh) {
      bf16x8 af, bfr[4];
      af = *(const bf16x8*)((const char*)&As[kh][0] + (w * 16) * 64 + foff);
#pragma unroll
      for (int nt = 0; nt < 4; ++nt)
        bfr[nt] = *(const bf16x8*)((const char*)&Bs[kh][0] +
                                   (nt * 16) * 64 + foff);
#pragma unroll
      for (int nt = 0; nt < 4; ++nt)
        acc[nt] = mfma16(af, bfr[nt], acc[nt]);
    }
  }

  const int m = m0 + w * 16 + lq * 4;
#pragma unroll
  for (int nt = 0; nt < 4; ++nt) {
    int n = n0 + nt * 16 + li;
    float bb = bias[n];
#pragma unroll
    for (int r = 0; r < 4; ++r)
      out[(size_t)(m + r) * C_ + n] = acc[nt][r] + bb;
  }
}

// ---------------------------------------------------------------------------
// Workspace (ushort offsets):
//   Qd 0 | Kd 4194304 | Vblk 8388608 | AO 12582912 | xb 16777216
//   wqkvT 20971520 | wprojT 21757952      (total ~44 MB)
// ---------------------------------------------------------------------------
extern "C" void kernel_launch(void* const* d_in, const int* in_sizes, int n_in,
                              void* d_out, int out_size, void* d_ws,
                              size_t ws_size, hipStream_t stream) {
  const float* x      = (const float*)d_in[0];
  const float* w_qkv  = (const float*)d_in[1];
  const float* b_qkv  = (const float*)d_in[2];
  const float* w_proj = (const float*)d_in[3];
  const float* b_proj = (const float*)d_in[4];
  float* out = (float*)d_out;

  ushort_t* ws     = (ushort_t*)d_ws;
  ushort_t* Qd     = ws;
  ushort_t* Kd     = ws + 4194304;
  ushort_t* Vd     = ws + 8388608;
  ushort_t* AO     = ws + 12582912;
  ushort_t* xb     = ws + 16777216;
  ushort_t* wqkvT  = ws + 20971520;
  ushort_t* wprojT = ws + 21757952;

  convert_all_kernel<<<2304, 256, 0, stream>>>(x, w_qkv, w_proj, xb, wqkvT,
                                               wprojT);

  dim3 g1(M_ / 128, N_QKV / 64);   // 64 x 24 = 1536
  qkv_mfma_kernel<<<g1, 256, 0, stream>>>(xb, wqkvT, b_qkv, Qd, Kd, Vd);

  attn_kernel<<<512, 512, 0, stream>>>(Qd, Kd, Vd, AO);

  dim3 g3(M_ / 64, C_ / 64);       // 128 x 8 = 1024
  proj_mfma_kernel<<<g3, 256, 0, stream>>>(AO, wprojT, b_proj, out);
}